// Round 12
// baseline (185.274 us; speedup 1.0000x reference)
//
#include <hip/hip_runtime.h>

// A8W8 GEMM, fp16-saturating output. C = (a_i8 @ b_i8^T) * arow * acol.
// Pass 1: pack int32 -> int8. Pass 2: 256x256 tile, BKB=128, 8 waves.
// A: LDS double-buffer, R5's verified staging+read swizzle (0 conflicts).
// B: DIRECT global->VGPR per wave (wave-private, L2-resident, 1-tile
// prefetch, ks-split) -- halves LDS port traffic and B needs no barrier.
// Per tile: chunked af read-ahead, 64 MFMA, ONE vmcnt(0)+BAR (drained
// loads are ~2500 cyc old => free).

constexpr int MD = 4096, ND = 4096, KD = 4096;
constexpr int BM = 256, BN = 256, BKB = 128;  // K-tile bytes (128 i8)
constexpr int NT = KD / BKB;                  // 32 K-tiles

using i32x4 = __attribute__((ext_vector_type(4))) int;

#define VMCNT(n) asm volatile("s_waitcnt vmcnt(" #n ")" ::: "memory")
#define BAR() __builtin_amdgcn_s_barrier()
#define FENCE() __builtin_amdgcn_sched_barrier(0)

// ---------------- pack: int32 (one value per elem) -> int8 ----------------
__global__ __launch_bounds__(256) void pack_i8(const int* __restrict__ in,
                                               char* __restrict__ out) {
  const size_t t = (size_t)blockIdx.x * 256 + threadIdx.x;
  const int4* p = (const int4*)in + t * 4;
  int4 v0 = p[0], v1 = p[1], v2 = p[2], v3 = p[3];
  int4 o;
  o.x = v0.x | (v0.y << 8) | (v0.z << 16) | (v0.w << 24);
  o.y = v1.x | (v1.y << 8) | (v1.z << 16) | (v1.w << 24);
  o.z = v2.x | (v2.y << 8) | (v2.z << 16) | (v2.w << 24);
  o.w = v3.x | (v3.y << 8) | (v3.z << 16) | (v3.w << 24);
  ((int4*)out)[t] = o;
}

// ---------------- GEMM ----------------------------------------------------
__device__ inline void load16_lds(const char* g, char* l) {
  __builtin_amdgcn_global_load_lds(
      (const __attribute__((address_space(1))) void*)g,
      (__attribute__((address_space(3))) void*)l, 16, 0, 0);
}

// reference fp16 cast, saturating (all values >= 0; |inf-finite|=inf passes)
__device__ inline float f16_sat(float v) {
  v = fminf(v, 65504.0f);
  return (float)(_Float16)v;
}

__global__ __launch_bounds__(512, 2) void gemm_i8w8(
    const char* __restrict__ A, const char* __restrict__ B,
    const float* __restrict__ arow, const float* __restrict__ acol,
    float* __restrict__ out) {
  __shared__ char sA[2][BM * BKB];  // 2 x 32 KiB (A only)

  const int tid = threadIdx.x;
  const int wv = tid >> 6;
  const int lane = tid & 63;

  // XCD-aware bijective swizzle (nwg = 256, divisible by 8)
  const int bid = blockIdx.x;
  const int wg = (bid & 7) * 32 + (bid >> 3);
  const int brow = wg >> 4;
  const int bcol = wg & 15;

  // 2(M) x 4(N) wave grid; per-wave output 128 x 64
  const int wrow = (wv >> 2) * 128;
  const int wcol = (wv & 3) * 64;

  i32x4 acc[8][4] = {};

  // ---- A staging (R5-verified, byte-identical): each gload_lds = 8 rows
  // x 128B; LDS dest linear (lane l -> row +(l>>3), slot l&7); source
  // slot pre-swizzled (l&7)^(l>>3): LDS[row][s] = G[row][s^(row&7)].
  const int lr = lane >> 3;
  const int lsg = ((lane & 7) ^ lr) * 16;
  const int q0 = wv * 2, q1 = wv * 2 + 1;
  const int rA0 = (q0 >> 3) * 128 + (q0 & 7) * 8;  // rows {0-63,128-191}
  const int rA1 = (q1 >> 3) * 128 + (q1 & 7) * 8;
  const char* srcA0 = A + (size_t)(brow * BM + rA0 + lr) * KD + lsg;
  const char* srcA1 = A + (size_t)(brow * BM + rA1 + lr) * KD + lsg;
  const size_t skip64 = (size_t)64 * KD;

  auto STAGE_A = [&](int nb, size_t kb) {  // 4 gloads/wave, full A tile
    load16_lds(srcA0 + kb, sA[nb] + rA0 * BKB);
    load16_lds(srcA1 + kb, sA[nb] + rA1 * BKB);
    load16_lds(srcA0 + skip64 + kb, sA[nb] + (rA0 + 64) * BKB);
    load16_lds(srcA1 + skip64 + kb, sA[nb] + (rA1 + 64) * BKB);
  };

  // ---- A fragment reads (R5-verified, 0 conflicts): row = base+(lane&15);
  // G-slot = ks*4+(lane>>4); LDS slot = G-slot ^ (r&7).
  const int r = lane & 15;
  const int s0 = (((lane >> 4) + 0) ^ (r & 7)) * 16;  // ks=0
  const int s1 = (((lane >> 4) + 4) ^ (r & 7)) * 16;  // ks=1
  const int aBase = (wrow + r) * BKB;                 // + m*2048

  // ---- B direct-to-reg: lane l -> B-row bcol*BN + wcol + n*16 + (l&15),
  // K-offset kt*128 + ks*64 + (l>>4)*16. Same data the MFMA B-operand
  // needs (row l&15, k-bytes (l>>4)*16 of each 64B k-slice).
  const char* bP[4];
#pragma unroll
  for (int n = 0; n < 4; ++n)
    bP[n] = B + (size_t)(bcol * BN + wcol + n * 16 + r) * KD + (lane >> 4) * 16;

  i32x4 afX[4], afY[4], bfU[4][2], bfV[4][2];

#define RDCHUNK(dst, ks, mh)                                              \
  {                                                                       \
    const char* p_ = sA[cb] + aBase + (mh)*8192 + ((ks) ? s1 : s0);       \
    _Pragma("unroll") for (int j = 0; j < 4; ++j) dst[j] =                \
        *(const i32x4*)(p_ + j * 2048);                                   \
  }
#define MFMA16(af, bf, ks, mh)                                            \
  {                                                                       \
    __builtin_amdgcn_s_setprio(1);                                        \
    _Pragma("unroll") for (int j = 0; j < 4; ++j)                         \
        _Pragma("unroll") for (int n = 0; n < 4; ++n) acc[(mh)*4 + j][n] =\
        __builtin_amdgcn_mfma_i32_16x16x64_i8(af[j], bf[n][ks],           \
                                              acc[(mh)*4 + j][n], 0, 0, 0);\
    __builtin_amdgcn_s_setprio(0);                                        \
  }

  // ---- prologue: B(tile0) -> bfU; stage A(tile0); drain; publish
#pragma unroll
  for (int n = 0; n < 4; ++n) {
    bfU[n][0] = *(const i32x4*)(bP[n] + 0);
    bfU[n][1] = *(const i32x4*)(bP[n] + 64);
  }
  STAGE_A(0, 0);
  VMCNT(0);
  BAR();

  // ---- one K-tile: B-prefetch (ks-split) + A-stage + chunked af
  // read-ahead + 64 MFMA + vmcnt(0) + BAR.
  auto tile = [&](int i, int cb_, int nb, i32x4(&bfC)[4][2],
                  i32x4(&bfN)[4][2]) {
    const int cb = cb_;
    const bool more = (i + 1) < NT;
    const size_t kb = (size_t)(i + 1) * BKB;
    if (more) {  // B ks0 prefetch (4 loads), then A stage (4 gloads)
#pragma unroll
      for (int n = 0; n < 4; ++n)
        bfN[n][0] = *(const i32x4*)(bP[n] + kb);
      FENCE();
      STAGE_A(nb, kb);
    }
    FENCE();
    RDCHUNK(afX, 0, 0);   // chunk c0
    RDCHUNK(afY, 0, 1);   // read-ahead c1
    MFMA16(afX, bfC, 0, 0);
    if (more) {  // B ks1 prefetch mid-tile
#pragma unroll
      for (int n = 0; n < 4; ++n)
        bfN[n][1] = *(const i32x4*)(bP[n] + kb + 64);
    }
    FENCE();
    RDCHUNK(afX, 1, 0);   // read-ahead c2
    MFMA16(afY, bfC, 0, 1);
    FENCE();
    RDCHUNK(afY, 1, 1);   // read-ahead c3
    MFMA16(afX, bfC, 1, 0);
    FENCE();
    MFMA16(afY, bfC, 1, 1);
    VMCNT(0);  // loads issued ~2500 cyc ago -> ~free; publishes A(nb)
    BAR();
  };

  for (int i = 0; i < NT; i += 2) {  // static buffer + bf parity
    tile(i, 0, 1, bfU, bfV);
    tile(i + 1, 1, 0, bfV, bfU);
  }

  // ---- epilogue: C/D map col=lane&15, row=(lane>>4)*4+reg (16x16 shapes)
  const int orow0 = brow * BM + wrow + ((lane >> 4) << 2);
  const int ocol0 = bcol * BN + wcol + (lane & 15);
#pragma unroll
  for (int m = 0; m < 8; ++m) {
    const int rb = orow0 + m * 16;
    const float ar0 = arow[rb + 0], ar1 = arow[rb + 1];
    const float ar2 = arow[rb + 2], ar3 = arow[rb + 3];
#pragma unroll
    for (int n = 0; n < 4; ++n) {
      const int col = ocol0 + n * 16;
      const float ac = acol[col];
      out[(size_t)(rb + 0) * ND + col] = f16_sat((float)acc[m][n][0] * (ar0 * ac));
      out[(size_t)(rb + 1) * ND + col] = f16_sat((float)acc[m][n][1] * (ar1 * ac));
      out[(size_t)(rb + 2) * ND + col] = f16_sat((float)acc[m][n][2] * (ar2 * ac));
      out[(size_t)(rb + 3) * ND + col] = f16_sat((float)acc[m][n][3] * (ar3 * ac));
    }
  }
}

extern "C" void kernel_launch(void* const* d_in, const int* in_sizes, int n_in,
                              void* d_out, int out_size, void* d_ws, size_t ws_size,
                              hipStream_t stream) {
  const int* a = (const int*)d_in[0];         // [M,K] int32 (int8 values)
  const int* b = (const int*)d_in[1];         // [N,K] int32 (int8 values)
  const float* arow = (const float*)d_in[2];  // [M,1]
  const float* acol = (const float*)d_in[3];  // [1,N]
  float* out = (float*)d_out;

  char* pa = (char*)d_ws;                    // 16 MiB packed A
  char* pb = pa + (size_t)MD * KD;           // 16 MiB packed B

  const int packBlocks = (int)(((size_t)MD * KD) / (16 * 256));  // 4096
  pack_i8<<<packBlocks, 256, 0, stream>>>(a, pa);
  pack_i8<<<packBlocks, 256, 0, stream>>>(b, pb);

  const int grid = (MD / BM) * (ND / BN);  // 256 blocks, 1 per CU
  gemm_i8w8<<<grid, 512, 0, stream>>>(pa, pb, arow, acol, out);
}

// Round 13
// 152.525 us; speedup vs baseline: 1.2147x; 1.2147x over previous
//
#include <hip/hip_runtime.h>

// A8W8 GEMM, fp16-saturating output. C = (a_i8 @ b_i8^T) * arow * acol.
// Pass 1: pack int32 -> int8. Pass 2: 256x256 tile, BKB=128, 8 waves.
// A: LDS dbuf with R5's verified staging+read swizzle (0 conflicts).
// B: direct global->VGPR, ONE ks-set in flight (bfU=ks0, bfV=ks1; 32
// regs total) issued ~2 clusters ahead of use -- register-lean fix of
// R12's spill. XCD remap gives each XCD 2 B panels (2MB, L2-resident).
// Per tile: 4x16-MFMA clusters, af chunk read-ahead, 1 barrier, counted
// vmcnt for the gload_lds publish (FIFO-proved).

constexpr int MD = 4096, ND = 4096, KD = 4096;
constexpr int BM = 256, BN = 256, BKB = 128;  // K-tile bytes (128 i8)
constexpr int NT = KD / BKB;                  // 32 K-tiles

using i32x4 = __attribute__((ext_vector_type(4))) int;

#define VMCNT(n) asm volatile("s_waitcnt vmcnt(" #n ")" ::: "memory")
#define BAR() __builtin_amdgcn_s_barrier()
#define FENCE() __builtin_amdgcn_sched_barrier(0)

// ---------------- pack: int32 (one value per elem) -> int8 ----------------
__global__ __launch_bounds__(256) void pack_i8(const int* __restrict__ in,
                                               char* __restrict__ out) {
  const size_t t = (size_t)blockIdx.x * 256 + threadIdx.x;
  const int4* p = (const int4*)in + t * 4;
  int4 v0 = p[0], v1 = p[1], v2 = p[2], v3 = p[3];
  int4 o;
  o.x = v0.x | (v0.y << 8) | (v0.z << 16) | (v0.w << 24);
  o.y = v1.x | (v1.y << 8) | (v1.z << 16) | (v1.w << 24);
  o.z = v2.x | (v2.y << 8) | (v2.z << 16) | (v2.w << 24);
  o.w = v3.x | (v3.y << 8) | (v3.z << 16) | (v3.w << 24);
  ((int4*)out)[t] = o;
}

// ---------------- GEMM ----------------------------------------------------
__device__ inline void load16_lds(const char* g, char* l) {
  __builtin_amdgcn_global_load_lds(
      (const __attribute__((address_space(1))) void*)g,
      (__attribute__((address_space(3))) void*)l, 16, 0, 0);
}

// reference fp16 cast, saturating (all values >= 0; |inf-finite|=inf passes)
__device__ inline float f16_sat(float v) {
  v = fminf(v, 65504.0f);
  return (float)(_Float16)v;
}

__global__ __launch_bounds__(512, 2) void gemm_i8w8(
    const char* __restrict__ A, const char* __restrict__ B,
    const float* __restrict__ arow, const float* __restrict__ acol,
    float* __restrict__ out) {
  __shared__ char sA[2][BM * BKB];  // 2 x 32 KiB (A only)

  const int tid = threadIdx.x;
  const int wv = tid >> 6;
  const int lane = tid & 63;

  // XCD remap: each XCD (bid&7) owns 2 bcol panels (2 MB B in 4 MB L2);
  // bijective over 256 blocks.
  const int bid = blockIdx.x;
  const int brow = bid >> 4;                             // 0..15
  const int bcol = (bid & 7) * 2 + ((bid >> 3) & 1);     // 0..15

  // 2(M) x 4(N) wave grid; per-wave output 128 x 64
  const int wrow = (wv >> 2) * 128;
  const int wcol = (wv & 3) * 64;

  i32x4 acc[8][4] = {};

  // ---- A staging (R5-verified, byte-identical): each gload_lds = 8 rows
  // x 128B; LDS dest linear (lane l -> row +(l>>3), slot l&7); source
  // slot pre-swizzled (l&7)^(l>>3): LDS[row][s] = G[row][s^(row&7)].
  const int lr = lane >> 3;
  const int lsg = ((lane & 7) ^ lr) * 16;
  const int q0 = wv * 2, q1 = wv * 2 + 1;
  const int rA0 = (q0 >> 3) * 128 + (q0 & 7) * 8;  // rows {0-63,128-191}
  const int rA1 = (q1 >> 3) * 128 + (q1 & 7) * 8;
  const char* srcA0 = A + (size_t)(brow * BM + rA0 + lr) * KD + lsg;
  const char* srcA1 = A + (size_t)(brow * BM + rA1 + lr) * KD + lsg;
  const size_t skip64 = (size_t)64 * KD;

  auto STAGE_A = [&](int nb, size_t kb) {  // 4 gloads/wave, full A tile
    load16_lds(srcA0 + kb, sA[nb] + rA0 * BKB);
    load16_lds(srcA1 + kb, sA[nb] + rA1 * BKB);
    load16_lds(srcA0 + skip64 + kb, sA[nb] + (rA0 + 64) * BKB);
    load16_lds(srcA1 + skip64 + kb, sA[nb] + (rA1 + 64) * BKB);
  };

  // ---- A fragment reads (R5-verified, 0 conflicts): row = base+(lane&15);
  // G-slot = ks*4+(lane>>4); LDS slot = G-slot ^ (r&7).
  const int r = lane & 15;
  const int s0 = (((lane >> 4) + 0) ^ (r & 7)) * 16;  // ks=0
  const int s1 = (((lane >> 4) + 4) ^ (r & 7)) * 16;  // ks=1
  const int aBase = (wrow + r) * BKB;                 // + m*2048

  // ---- B direct-to-reg: lane l needs B[row wcol+n*16+r][k-bytes
  // i*128 + ks*64 + (l>>4)*16] -- byte-identical to what the LDS path
  // delivered. 4 rows x 64B contiguous per load group (L2-resident).
  const char* bPtr =
      B + (size_t)(bcol * BN + wcol + r) * KD + (lane >> 4) * 16;

  i32x4 afX[4], afY[4], bfU[4], bfV[4];

  auto LOAD_B = [&](i32x4(&bf)[4], size_t koff) {
#pragma unroll
    for (int n = 0; n < 4; ++n)
      bf[n] = *(const i32x4*)(bPtr + (size_t)(n * 16) * KD + koff);
  };
  auto RD_A = [&](i32x4(&af)[4], int buf, int mh, int ks) {
    const char* p = sA[buf] + aBase + mh * 8192 + (ks ? s1 : s0);
#pragma unroll
    for (int j = 0; j < 4; ++j) af[j] = *(const i32x4*)(p + j * 2048);
  };
  auto MFMA16 = [&](i32x4(&af)[4], i32x4(&bf)[4], int mh) {
    __builtin_amdgcn_s_setprio(1);
#pragma unroll
    for (int j = 0; j < 4; ++j)
#pragma unroll
      for (int n = 0; n < 4; ++n)
        acc[mh * 4 + j][n] = __builtin_amdgcn_mfma_i32_16x16x64_i8(
            af[j], bf[n], acc[mh * 4 + j][n], 0, 0, 0);
    __builtin_amdgcn_s_setprio(0);
  };

  // ---- prologue: B(0,ks0)->bfU; stage A(0); drain; publish; read afX
  LOAD_B(bfU, 0);
  STAGE_A(0, 0);
  VMCNT(0);
  BAR();
  RD_A(afX, 0, 0, 0);

  // ---- one K-tile: clusters (mh0,ks0)(mh1,ks0)(mh0,ks1)(mh1,ks1).
  // FIFO: [bfV(4), stage(4)] then c2 issues [bfU'(4)].
  auto tile = [&](int i, int cb, int nb) {
    const bool more = (i + 1) < NT;
    const size_t kb = (size_t)(i + 1) * BKB;
    // c0: issue bfV (this tile ks1) + stage(next); afY<-(mh1,ks0); MFMA
    LOAD_B(bfV, (size_t)i * BKB + 64);
    if (more) STAGE_A(nb, kb);
    FENCE();
    RD_A(afY, cb, 1, 0);
    MFMA16(afX, bfU, 0);
    // c1: afX<-(mh0,ks1); MFMA; retire bfV (stage stays in flight)
    RD_A(afX, cb, 0, 1);
    MFMA16(afY, bfU, 1);
    if (more) VMCNT(4); else VMCNT(0);
    // c2: issue bfU' (next tile ks0); afY<-(mh1,ks1); MFMA
    if (more) {
      LOAD_B(bfU, kb);
      FENCE();
    }
    RD_A(afY, cb, 1, 1);
    MFMA16(afX, bfV, 0);
    // c3: MFMA; retire stage (bfU' rides across the barrier, auto-waited
    // at first use next tile, ~2 clusters of lead); publish; read afX'
    MFMA16(afY, bfV, 1);
    if (more) VMCNT(4); else VMCNT(0);
    BAR();
    if (more) RD_A(afX, nb, 0, 0);
  };

  for (int i = 0; i < NT; i += 2) {  // static buffer parity
    tile(i, 0, 1);
    tile(i + 1, 1, 0);
  }

  // ---- epilogue: C/D map col=lane&15, row=(lane>>4)*4+reg (16x16 shapes)
  const int orow0 = brow * BM + wrow + ((lane >> 4) << 2);
  const int ocol0 = bcol * BN + wcol + (lane & 15);
#pragma unroll
  for (int m = 0; m < 8; ++m) {
    const int rb = orow0 + m * 16;
    const float ar0 = arow[rb + 0], ar1 = arow[rb + 1];
    const float ar2 = arow[rb + 2], ar3 = arow[rb + 3];
#pragma unroll
    for (int n = 0; n < 4; ++n) {
      const int col = ocol0 + n * 16;
      const float ac = acol[col];
      out[(size_t)(rb + 0) * ND + col] = f16_sat((float)acc[m][n][0] * (ar0 * ac));
      out[(size_t)(rb + 1) * ND + col] = f16_sat((float)acc[m][n][1] * (ar1 * ac));
      out[(size_t)(rb + 2) * ND + col] = f16_sat((float)acc[m][n][2] * (ar2 * ac));
      out[(size_t)(rb + 3) * ND + col] = f16_sat((float)acc[m][n][3] * (ar3 * ac));
    }
  }
}

extern "C" void kernel_launch(void* const* d_in, const int* in_sizes, int n_in,
                              void* d_out, int out_size, void* d_ws, size_t ws_size,
                              hipStream_t stream) {
  const int* a = (const int*)d_in[0];         // [M,K] int32 (int8 values)
  const int* b = (const int*)d_in[1];         // [N,K] int32 (int8 values)
  const float* arow = (const float*)d_in[2];  // [M,1]
  const float* acol = (const float*)d_in[3];  // [1,N]
  float* out = (float*)d_out;

  char* pa = (char*)d_ws;                    // 16 MiB packed A
  char* pb = pa + (size_t)MD * KD;           // 16 MiB packed B

  const int packBlocks = (int)(((size_t)MD * KD) / (16 * 256));  // 4096
  pack_i8<<<packBlocks, 256, 0, stream>>>(a, pa);
  pack_i8<<<packBlocks, 256, 0, stream>>>(b, pb);

  const int grid = (MD / BM) * (ND / BN);  // 256 blocks, 1 per CU
  gemm_i8w8<<<grid, 512, 0, stream>>>(pa, pb, arow, acol, out);
}